// Round 10
// baseline (249.337 us; speedup 1.0000x reference)
//
#include <hip/hip_runtime.h>
#include <math.h>

#define BB 2
#define LL 2048
#define DIMM 1024
#define HH 16
#define DD 64
#define QKV_N 3072

typedef unsigned short u16;
typedef unsigned int u32;
typedef __attribute__((ext_vector_type(8))) short short8;   // 8 x bf16
typedef __attribute__((ext_vector_type(4))) float f32x4;

__device__ __forceinline__ float bf2f(u16 h) {
    unsigned u = ((unsigned)h) << 16;
    return __uint_as_float(u);
}
__device__ __forceinline__ u16 f2bf(float f) {
    unsigned u = __float_as_uint(f);
    u += 0x7fffu + ((u >> 16) & 1u);   // round-to-nearest-even
    return (u16)(u >> 16);
}
// pack two f32 -> (bf16(hi)<<16)|bf16(lo), round-half-up
__device__ __forceinline__ u32 pack_bf2(float lo, float hi) {
    u32 a = __float_as_uint(hi) + 0x8000u;
    u32 b = __float_as_uint(lo) + 0x8000u;
    return __builtin_amdgcn_perm(a, b, 0x07060302u);
}
// async global->LDS, 16B per lane; LDS dst is wave-uniform base + lane*16
__device__ __forceinline__ void gload16(const u16* g, u16* l) {
    __builtin_amdgcn_global_load_lds(
        (const __attribute__((address_space(1))) void*)g,
        (__attribute__((address_space(3))) void*)l, 16, 0, 0);
}

// ---------------- f32 -> bf16 convert (x) -------------------------------------
__global__ __launch_bounds__(256) void convx(
    const float* __restrict__ X, u16* __restrict__ Xb)
{
    int i = (blockIdx.x * 256 + threadIdx.x) * 8;
    float4 a = *(const float4*)&X[i];
    float4 b = *(const float4*)&X[i + 4];
    u16 t[8] = {f2bf(a.x), f2bf(a.y), f2bf(a.z), f2bf(a.w),
                f2bf(b.x), f2bf(b.y), f2bf(b.z), f2bf(b.w)};
    *(uint4*)&Xb[i] = *(uint4*)t;
}

// ---------------- f32 [K,N] -> bf16 [N,K] transpose-convert -------------------
__global__ __launch_bounds__(256) void convt(
    const float* __restrict__ W, u16* __restrict__ Wt, int K, int N)
{
    __shared__ u16 s[64][72];
    const int tid = threadIdx.x;
    const int k0 = blockIdx.x * 64, n0 = blockIdx.y * 64;
#pragma unroll
    for (int t = 0; t < 16; ++t) {
        int flat = t * 256 + tid;
        int kk = flat >> 6, nn = flat & 63;
        s[nn][kk] = f2bf(W[(size_t)(k0 + kk) * N + n0 + nn]);
    }
    __syncthreads();
#pragma unroll
    for (int t = 0; t < 2; ++t) {
        int chunk = t * 256 + tid;
        int nn = chunk >> 3, kc = chunk & 7;
        *(uint4*)&Wt[(size_t)(n0 + nn) * K + k0 + kc * 8] = *(uint4*)&s[nn][kc * 8];
    }
}

// ---------------- QKV GEMM (global_load_lds staging) + fused epilogues --------
// q/k tiles: RMSNorm + RoPE on f32 accs -> bf16 qkv.
// v tiles: LDS-transpose -> direct store to vt[b,h,d,l] (vtrans kernel fused).
__global__ __launch_bounds__(256) void gemm_qkv(
    const u16* __restrict__ A, const u16* __restrict__ Bt,
    u16* __restrict__ C, u16* __restrict__ vt, const float* __restrict__ pe,
    const float* __restrict__ qs, const float* __restrict__ ks)
{
    __shared__ u16 smem[2 * 128 * 64];   // sA | sB; reused for v transpose
    u16* sA = smem;
    u16* sB = smem + 128 * 64;

    const int tid = threadIdx.x;
    const int wave = tid >> 6, lane = tid & 63;
    const int mIdx = lane & 15, quad = lane >> 4;
    const int wr = wave >> 1, wc = wave & 1;
    const int m0 = blockIdx.y * 128, n0 = blockIdx.x * 128;
    const int N = QKV_N, K = DIMM;
    const int lr = lane >> 3, lc = lane & 7;

    f32x4 acc[4][4];
#pragma unroll
    for (int a = 0; a < 4; ++a)
#pragma unroll
        for (int b = 0; b < 4; ++b) acc[a][b] = (f32x4){0.f, 0.f, 0.f, 0.f};

    for (int k0 = 0; k0 < K; k0 += 64) {
#pragma unroll
        for (int j = 0; j < 4; ++j) {
            int r0 = 32 * wave + 8 * j + lr;
            int kc = 8 * (lc ^ (r0 & 7));
            gload16(&A[(size_t)(m0 + r0) * K + k0 + kc], &sA[(32 * wave + 8 * j) * 64]);
            gload16(&Bt[(size_t)(n0 + r0) * K + k0 + kc], &sB[(32 * wave + 8 * j) * 64]);
        }
        __syncthreads();
#pragma unroll
        for (int ks2 = 0; ks2 < 2; ++ks2) {
            short8 af[4], bfr[4];
#pragma unroll
            for (int mt = 0; mt < 4; ++mt) {
                int Ra = 64 * wr + 16 * mt + mIdx;
                af[mt] = *(const short8*)&sA[Ra * 64 + 8 * ((ks2 * 4 + quad) ^ (Ra & 7))];
            }
#pragma unroll
            for (int nt = 0; nt < 4; ++nt) {
                int Rb = 64 * wc + 16 * nt + mIdx;
                bfr[nt] = *(const short8*)&sB[Rb * 64 + 8 * ((ks2 * 4 + quad) ^ (Rb & 7))];
            }
#pragma unroll
            for (int mt = 0; mt < 4; ++mt)
#pragma unroll
                for (int nt = 0; nt < 4; ++nt)
                    acc[mt][nt] = __builtin_amdgcn_mfma_f32_16x16x32_bf16(
                        af[mt], bfr[nt], acc[mt][nt], 0, 0, 0);
        }
        __syncthreads();
    }

    if (n0 >= 2048) {
        // ---- v region: transpose tile through LDS, store to vt[b,h,d,l] ----
        // write: lane's 4 row-contiguous values -> one uint2 at [d][l ^ sw]
#pragma unroll
        for (int mt = 0; mt < 4; ++mt) {
            int lofs = 64 * wr + 16 * mt + 4 * quad;
#pragma unroll
            for (int nt = 0; nt < 4; ++nt) {
                int d = 64 * wc + 16 * nt + mIdx;
                uint2 pr;
                pr.x = pack_bf2(acc[mt][nt][0], acc[mt][nt][1]);
                pr.y = pack_bf2(acc[mt][nt][2], acc[mt][nt][3]);
                *(uint2*)&smem[d * 128 + (lofs ^ (8 * (d & 7)))] = pr;
            }
        }
        __syncthreads();
        // read rows (coalesced along l) and store: 2 threads per d-row
        {
            const int d = tid >> 1, half = tid & 1;
            const int hd = n0 - 2048 + d;
            const int h = hd >> 6, dd = hd & 63;
            const int b = m0 >> 11, l0 = m0 & 2047;
            u16* dst = vt + ((size_t)((b * 16 + h) * 64 + dd)) * LL + l0 + half * 64;
#pragma unroll
            for (int c = 0; c < 8; ++c) {
                int slot = (half * 64 + 8 * c) ^ (8 * (d & 7));
                *(uint4*)&dst[8 * c] = *(const uint4*)&smem[d * 128 + slot];
            }
        }
    } else {
        // ---- q/k region: RMSNorm over head dim + RoPE; q prescaled log2e/8 --
        const float* scv = (n0 < 1024) ? qs : ks;
        const float pre = (n0 < 1024) ? 0.18033688011112042f : 1.0f;
        float scl[4];
#pragma unroll
        for (int nt = 0; nt < 4; ++nt) scl[nt] = scv[16 * nt + mIdx];

#pragma unroll
        for (int mt = 0; mt < 4; ++mt) {
#pragma unroll
            for (int r = 0; r < 4; ++r) {
                float s = 0.f;
#pragma unroll
                for (int nt = 0; nt < 4; ++nt) {
                    float a = acc[mt][nt][r];
                    s += a * a;
                }
                s += __shfl_xor(s, 1);
                s += __shfl_xor(s, 2);
                s += __shfl_xor(s, 4);
                s += __shfl_xor(s, 8);
                float rn = rsqrtf(s * (1.f / 64.f) + 1e-6f);
                int R = m0 + 64 * wr + 16 * mt + quad * 4 + r;   // = b*L + l
                size_t peo = (size_t)R * 128;
#pragma unroll
                for (int nt = 0; nt < 4; ++nt) {
                    float v = acc[mt][nt][r] * rn * scl[nt];
                    float pp = __shfl_xor(v, 1);
                    float2 pw = *(const float2*)&pe[peo + 2 * (16 * nt + mIdx)];
                    float e  = (mIdx & 1) ? pp : v;
                    float od = (mIdx & 1) ? v : pp;
                    C[(size_t)R * N + n0 + 64 * wc + 16 * nt + mIdx] =
                        f2bf((pw.x * e + pw.y * od) * pre);
                }
            }
        }
    }
}

// ---------------- proj GEMM (global_load_lds staging, 64x128 tile) ------------
__global__ __launch_bounds__(256) void gemm_proj(
    const u16* __restrict__ A, const u16* __restrict__ Bt,
    const float* __restrict__ bias, float* __restrict__ C)
{
    __shared__ u16 sA[64 * 64];
    __shared__ u16 sB[128 * 64];

    const int tid = threadIdx.x;
    const int wave = tid >> 6, lane = tid & 63;
    const int mIdx = lane & 15, quad = lane >> 4;
    const int wr = wave >> 1, wc = wave & 1;   // 2x2 waves of 32x64
    const int m0 = blockIdx.y * 64, n0 = blockIdx.x * 128;
    const int N = DIMM, K = DIMM;
    const int lr = lane >> 3, lc = lane & 7;

    f32x4 acc[2][4];
#pragma unroll
    for (int a = 0; a < 2; ++a)
#pragma unroll
        for (int b = 0; b < 4; ++b) acc[a][b] = (f32x4){0.f, 0.f, 0.f, 0.f};

    for (int k0 = 0; k0 < K; k0 += 64) {
#pragma unroll
        for (int j = 0; j < 2; ++j) {       // A: 64 rows
            int r0 = 16 * wave + 8 * j + lr;
            int kc = 8 * (lc ^ (r0 & 7));
            gload16(&A[(size_t)(m0 + r0) * K + k0 + kc], &sA[(16 * wave + 8 * j) * 64]);
        }
#pragma unroll
        for (int j = 0; j < 4; ++j) {       // B: 128 rows
            int r0 = 32 * wave + 8 * j + lr;
            int kc = 8 * (lc ^ (r0 & 7));
            gload16(&Bt[(size_t)(n0 + r0) * K + k0 + kc], &sB[(32 * wave + 8 * j) * 64]);
        }
        __syncthreads();
#pragma unroll
        for (int ks2 = 0; ks2 < 2; ++ks2) {
            short8 af[2], bfr[4];
#pragma unroll
            for (int mt = 0; mt < 2; ++mt) {
                int Ra = 32 * wr + 16 * mt + mIdx;
                af[mt] = *(const short8*)&sA[Ra * 64 + 8 * ((ks2 * 4 + quad) ^ (Ra & 7))];
            }
#pragma unroll
            for (int nt = 0; nt < 4; ++nt) {
                int Rb = 64 * wc + 16 * nt + mIdx;
                bfr[nt] = *(const short8*)&sB[Rb * 64 + 8 * ((ks2 * 4 + quad) ^ (Rb & 7))];
            }
#pragma unroll
            for (int mt = 0; mt < 2; ++mt)
#pragma unroll
                for (int nt = 0; nt < 4; ++nt)
                    acc[mt][nt] = __builtin_amdgcn_mfma_f32_16x16x32_bf16(
                        af[mt], bfr[nt], acc[mt][nt], 0, 0, 0);
        }
        __syncthreads();
    }

#pragma unroll
    for (int mt = 0; mt < 2; ++mt)
#pragma unroll
        for (int r = 0; r < 4; ++r) {
            int row = m0 + 32 * wr + 16 * mt + quad * 4 + r;
#pragma unroll
            for (int nt = 0; nt < 4; ++nt) {
                int col = n0 + 64 * wc + 16 * nt + mIdx;
                C[(size_t)row * N + col] = acc[mt][nt][r] + bias[col];
            }
        }
}

// ---------------- flash attention v3: 2 q-strips/wave, async staging ----------
// 256 thr = 4 waves x 32 q-rows (2 strips of 16, sharing K/V frag reads);
// 128 q-rows/block, grid 512. Single-buffered UNPADDED K/V tiles staged via
// global_load_lds (XOR chunk swizzle on the GLOBAL source address so b128
// frag reads spread banks). sP stride 68 (<=2-way). 2 barriers/iter.
// LDS = 8.2+8.2+17.4 = 33.8 KB -> 4 blocks/CU = 16 waves/CU.
// NO min-waves launch bound (R7 lesson), NO cross-iter registers.
#define PPR 68

__global__ __launch_bounds__(256) void attn_mfma(
    const u16* __restrict__ qkv, const u16* __restrict__ vt, u16* __restrict__ o)
{
    __shared__ u16 sK[64 * 64];
    __shared__ u16 sVt[64 * 64];
    __shared__ u16 sP[128 * PPR];

    const int tid = threadIdx.x;
    const int wave = tid >> 6;      // 0..3
    const int lane = tid & 63;
    const int mIdx = lane & 15;
    const int quad = lane >> 4;
    const int lr = lane >> 3, lc = lane & 7;

    const int bh = blockIdx.x >> 4;    // 16 q-tiles of 128 rows per (b,h)
    const int qt = blockIdx.x & 15;
    const int b = bh >> 4, h = bh & 15;
    const int q0 = qt * 128;

    const u16* kbase = qkv + (size_t)b * LL * QKV_N + 1024 + h * 64;
    const u16* vbase = vt + (size_t)bh * 64 * LL;

    // Q B-operand frags for the wave's 2 strips (wave-private rows)
    short8 aq[2][2];
#pragma unroll
    for (int s2 = 0; s2 < 2; ++s2) {
        const u16* qrow = qkv
            + ((size_t)(b * LL + q0 + 32 * wave + 16 * s2 + mIdx)) * QKV_N + h * 64;
        aq[s2][0] = *(const short8*)&qrow[quad * 8];
        aq[s2][1] = *(const short8*)&qrow[32 + quad * 8];
    }

    float lsum[2] = {0.f, 0.f};
    f32x4 Oacc[2][4];
#pragma unroll
    for (int s2 = 0; s2 < 2; ++s2)
#pragma unroll
        for (int nb = 0; nb < 4; ++nb) Oacc[s2][nb] = (f32x4){0.f, 0.f, 0.f, 0.f};

    u16* sProw[2] = { &sP[(32 * wave + mIdx) * PPR],
                      &sP[(32 * wave + 16 + mIdx) * PPR] };

    for (int kt = 0; kt < 32; ++kt) {
        const int k0 = kt * 64;
        __syncthreads();   // previous iter's sK/sVt reads complete

        // async staging: each wave 2 K + 2 V instructions (8 rows each)
#pragma unroll
        for (int j = 0; j < 2; ++j) {
            int r0 = 16 * wave + 8 * j + lr;        // local key row / d row
            int kc = 8 * (lc ^ (r0 & 7));
            gload16(&kbase[(size_t)(k0 + r0) * QKV_N + kc], &sK[(16 * wave + 8 * j) * 64]);
            gload16(&vbase[(size_t)r0 * LL + k0 + kc], &sVt[(16 * wave + 8 * j) * 64]);
        }
        __syncthreads();   // vmcnt drained: staged tile visible

        // ---- S^T: 64 keys x 32 q; K-frags shared across strips ----
        f32x4 st[2][4];
#pragma unroll
        for (int nb = 0; nb < 4; ++nb) {
            int rowK = 16 * nb + mIdx;
            short8 bk0 = *(const short8*)&sK[rowK * 64 + 8 * (quad ^ (rowK & 7))];
            short8 bk1 = *(const short8*)&sK[rowK * 64 + 8 * ((4 + quad) ^ (rowK & 7))];
#pragma unroll
            for (int s2 = 0; s2 < 2; ++s2) {
                f32x4 a = (f32x4){0.f, 0.f, 0.f, 0.f};
                a = __builtin_amdgcn_mfma_f32_16x16x32_bf16(bk0, aq[s2][0], a, 0, 0, 0);
                a = __builtin_amdgcn_mfma_f32_16x16x32_bf16(bk1, aq[s2][1], a, 0, 0, 0);
                st[s2][nb] = a;
            }
        }

        // ---- softmax (exp2 domain, no running max), pack P to LDS ----
#pragma unroll
        for (int s2 = 0; s2 < 2; ++s2) {
#pragma unroll
            for (int nb = 0; nb < 4; ++nb) {
                float p0 = exp2f(st[s2][nb][0]), p1 = exp2f(st[s2][nb][1]);
                float p2 = exp2f(st[s2][nb][2]), p3 = exp2f(st[s2][nb][3]);
                lsum[s2] += (p0 + p1) + (p2 + p3);
                uint2 pr;
                pr.x = pack_bf2(p0, p1);
                pr.y = pack_bf2(p2, p3);
                *(uint2*)&sProw[s2][16 * nb + quad * 4] = pr;
            }
        }

        // ---- O += P @ V; V-frags shared across strips; sP wave-private ----
        short8 pa[2][2];
#pragma unroll
        for (int s2 = 0; s2 < 2; ++s2) {
            pa[s2][0] = *(const short8*)&sProw[s2][quad * 8];
            pa[s2][1] = *(const short8*)&sProw[s2][32 + quad * 8];
        }
#pragma unroll
        for (int nb = 0; nb < 4; ++nb) {
            int rowV = 16 * nb + mIdx;
            short8 bv0 = *(const short8*)&sVt[rowV * 64 + 8 * (quad ^ (rowV & 7))];
            short8 bv1 = *(const short8*)&sVt[rowV * 64 + 8 * ((4 + quad) ^ (rowV & 7))];
#pragma unroll
            for (int s2 = 0; s2 < 2; ++s2) {
                Oacc[s2][nb] = __builtin_amdgcn_mfma_f32_16x16x32_bf16(
                    pa[s2][0], bv0, Oacc[s2][nb], 0, 0, 0);
                Oacc[s2][nb] = __builtin_amdgcn_mfma_f32_16x16x32_bf16(
                    pa[s2][1], bv1, Oacc[s2][nb], 0, 0, 0);
            }
        }
    }

    // epilogue: per strip, reduce l across quads, normalize, store bf16
#pragma unroll
    for (int s2 = 0; s2 < 2; ++s2) {
        float ls = lsum[s2];
        ls += __shfl_xor(ls, 16);
        ls += __shfl_xor(ls, 32);
#pragma unroll
        for (int r = 0; r < 4; ++r) {
            float lr2 = __shfl(ls, quad * 4 + r);
            float linv = 1.f / lr2;
            int rowg = b * LL + q0 + 32 * wave + 16 * s2 + quad * 4 + r;
#pragma unroll
            for (int nb = 0; nb < 4; ++nb) {
                o[(size_t)rowg * DIMM + h * 64 + 16 * nb + mIdx] =
                    f2bf(Oacc[s2][nb][r] * linv);
            }
        }
    }
}

extern "C" void kernel_launch(void* const* d_in, const int* in_sizes, int n_in,
                              void* d_out, int out_size, void* d_ws, size_t ws_size,
                              hipStream_t stream) {
    const float* x       = (const float*)d_in[0];
    const float* pe      = (const float*)d_in[1];
    const float* w_qkv   = (const float*)d_in[2];
    const float* q_scale = (const float*)d_in[3];
    const float* k_scale = (const float*)d_in[4];
    const float* w_proj  = (const float*)d_in[5];
    const float* b_proj  = (const float*)d_in[6];
    float* out = (float*)d_out;

    char* ws = (char*)d_ws;
    u16* qkv    = (u16*)ws;  ws += (size_t)4096 * 3072 * 2;
    u16* o      = (u16*)ws;  ws += (size_t)4096 * 1024 * 2;
    u16* xb     = (u16*)ws;  ws += (size_t)4096 * 1024 * 2;
    u16* wqkvt  = (u16*)ws;  ws += (size_t)3072 * 1024 * 2;
    u16* wprojt = (u16*)ws;  ws += (size_t)1024 * 1024 * 2;
    u16* vtbuf  = (u16*)ws;  ws += (size_t)BB * HH * DD * LL * 2;

    // 0. conversions
    convx<<<(4096 * 1024) / (256 * 8), 256, 0, stream>>>(x, xb);
    convt<<<dim3(1024 / 64, QKV_N / 64), 256, 0, stream>>>(w_qkv, wqkvt, DIMM, QKV_N);
    convt<<<dim3(1024 / 64, 1024 / 64), 256, 0, stream>>>(w_proj, wprojt, DIMM, DIMM);

    // 1. fused QKV projection + RMSNorm/RoPE (q,k) + V-transpose (v) epilogues
    gemm_qkv<<<dim3(QKV_N / 128, (BB * LL) / 128), 256, 0, stream>>>(
        xb, wqkvt, qkv, vtbuf, pe, q_scale, k_scale);

    // 2. attention (2 q-strips/wave, async staging)
    attn_mfma<<<BB * HH * (LL / 128), 256, 0, stream>>>(qkv, vtbuf, o);

    // 3. output projection + bias (f32 out)
    gemm_proj<<<dim3(DIMM / 128, (BB * LL) / 64), 256, 0, stream>>>(
        o, wprojt, b_proj, out);
}

// Round 11
// 221.735 us; speedup vs baseline: 1.1245x; 1.1245x over previous
//
#include <hip/hip_runtime.h>
#include <math.h>

#define BB 2
#define LL 2048
#define DIMM 1024
#define HH 16
#define DD 64
#define QKV_N 3072

typedef unsigned short u16;
typedef unsigned int u32;
typedef __attribute__((ext_vector_type(8))) short short8;   // 8 x bf16
typedef __attribute__((ext_vector_type(4))) float f32x4;

__device__ __forceinline__ float bf2f(u16 h) {
    unsigned u = ((unsigned)h) << 16;
    return __uint_as_float(u);
}
__device__ __forceinline__ u16 f2bf(float f) {
    unsigned u = __float_as_uint(f);
    u += 0x7fffu + ((u >> 16) & 1u);   // round-to-nearest-even
    return (u16)(u >> 16);
}
// pack two f32 -> (bf16(hi)<<16)|bf16(lo), round-half-up
__device__ __forceinline__ u32 pack_bf2(float lo, float hi) {
    u32 a = __float_as_uint(hi) + 0x8000u;
    u32 b = __float_as_uint(lo) + 0x8000u;
    return __builtin_amdgcn_perm(a, b, 0x07060302u);
}
// async global->LDS, 16B per lane; LDS dst is wave-uniform base + lane*16
__device__ __forceinline__ void gload16(const u16* g, u16* l) {
    __builtin_amdgcn_global_load_lds(
        (const __attribute__((address_space(1))) void*)g,
        (__attribute__((address_space(3))) void*)l, 16, 0, 0);
}

// ---------------- f32 -> bf16 convert (x) -------------------------------------
__global__ __launch_bounds__(256) void convx(
    const float* __restrict__ X, u16* __restrict__ Xb)
{
    int i = (blockIdx.x * 256 + threadIdx.x) * 8;
    float4 a = *(const float4*)&X[i];
    float4 b = *(const float4*)&X[i + 4];
    u16 t[8] = {f2bf(a.x), f2bf(a.y), f2bf(a.z), f2bf(a.w),
                f2bf(b.x), f2bf(b.y), f2bf(b.z), f2bf(b.w)};
    *(uint4*)&Xb[i] = *(uint4*)t;
}

// ---------------- f32 [K,N] -> bf16 [N,K] transpose-convert -------------------
__global__ __launch_bounds__(256) void convt(
    const float* __restrict__ W, u16* __restrict__ Wt, int K, int N)
{
    __shared__ u16 s[64][72];
    const int tid = threadIdx.x;
    const int k0 = blockIdx.x * 64, n0 = blockIdx.y * 64;
#pragma unroll
    for (int t = 0; t < 16; ++t) {
        int flat = t * 256 + tid;
        int kk = flat >> 6, nn = flat & 63;
        s[nn][kk] = f2bf(W[(size_t)(k0 + kk) * N + n0 + nn]);
    }
    __syncthreads();
#pragma unroll
    for (int t = 0; t < 2; ++t) {
        int chunk = t * 256 + tid;
        int nn = chunk >> 3, kc = chunk & 7;
        *(uint4*)&Wt[(size_t)(n0 + nn) * K + k0 + kc * 8] = *(uint4*)&s[nn][kc * 8];
    }
}

// ---------------- QKV GEMM (global_load_lds staging) + fused epilogues --------
// q/k tiles: RMSNorm + RoPE on f32 accs -> bf16 qkv.
// v tiles: LDS-transpose -> direct store to vt[b,h,d,l] (vtrans kernel fused).
__global__ __launch_bounds__(256) void gemm_qkv(
    const u16* __restrict__ A, const u16* __restrict__ Bt,
    u16* __restrict__ C, u16* __restrict__ vt, const float* __restrict__ pe,
    const float* __restrict__ qs, const float* __restrict__ ks)
{
    __shared__ u16 smem[2 * 128 * 64];   // sA | sB; reused for v transpose
    u16* sA = smem;
    u16* sB = smem + 128 * 64;

    const int tid = threadIdx.x;
    const int wave = tid >> 6, lane = tid & 63;
    const int mIdx = lane & 15, quad = lane >> 4;
    const int wr = wave >> 1, wc = wave & 1;
    const int m0 = blockIdx.y * 128, n0 = blockIdx.x * 128;
    const int N = QKV_N, K = DIMM;
    const int lr = lane >> 3, lc = lane & 7;

    f32x4 acc[4][4];
#pragma unroll
    for (int a = 0; a < 4; ++a)
#pragma unroll
        for (int b = 0; b < 4; ++b) acc[a][b] = (f32x4){0.f, 0.f, 0.f, 0.f};

    for (int k0 = 0; k0 < K; k0 += 64) {
#pragma unroll
        for (int j = 0; j < 4; ++j) {
            int r0 = 32 * wave + 8 * j + lr;
            int kc = 8 * (lc ^ (r0 & 7));
            gload16(&A[(size_t)(m0 + r0) * K + k0 + kc], &sA[(32 * wave + 8 * j) * 64]);
            gload16(&Bt[(size_t)(n0 + r0) * K + k0 + kc], &sB[(32 * wave + 8 * j) * 64]);
        }
        __syncthreads();
#pragma unroll
        for (int ks2 = 0; ks2 < 2; ++ks2) {
            short8 af[4], bfr[4];
#pragma unroll
            for (int mt = 0; mt < 4; ++mt) {
                int Ra = 64 * wr + 16 * mt + mIdx;
                af[mt] = *(const short8*)&sA[Ra * 64 + 8 * ((ks2 * 4 + quad) ^ (Ra & 7))];
            }
#pragma unroll
            for (int nt = 0; nt < 4; ++nt) {
                int Rb = 64 * wc + 16 * nt + mIdx;
                bfr[nt] = *(const short8*)&sB[Rb * 64 + 8 * ((ks2 * 4 + quad) ^ (Rb & 7))];
            }
#pragma unroll
            for (int mt = 0; mt < 4; ++mt)
#pragma unroll
                for (int nt = 0; nt < 4; ++nt)
                    acc[mt][nt] = __builtin_amdgcn_mfma_f32_16x16x32_bf16(
                        af[mt], bfr[nt], acc[mt][nt], 0, 0, 0);
        }
        __syncthreads();
    }

    if (n0 >= 2048) {
        // ---- v region: transpose tile through LDS, store to vt[b,h,d,l] ----
#pragma unroll
        for (int mt = 0; mt < 4; ++mt) {
            int lofs = 64 * wr + 16 * mt + 4 * quad;
#pragma unroll
            for (int nt = 0; nt < 4; ++nt) {
                int d = 64 * wc + 16 * nt + mIdx;
                uint2 pr;
                pr.x = pack_bf2(acc[mt][nt][0], acc[mt][nt][1]);
                pr.y = pack_bf2(acc[mt][nt][2], acc[mt][nt][3]);
                *(uint2*)&smem[d * 128 + (lofs ^ (8 * (d & 7)))] = pr;
            }
        }
        __syncthreads();
        {
            const int d = tid >> 1, half = tid & 1;
            const int hd = n0 - 2048 + d;
            const int h = hd >> 6, dd = hd & 63;
            const int b = m0 >> 11, l0 = m0 & 2047;
            u16* dst = vt + ((size_t)((b * 16 + h) * 64 + dd)) * LL + l0 + half * 64;
#pragma unroll
            for (int c = 0; c < 8; ++c) {
                int slot = (half * 64 + 8 * c) ^ (8 * (d & 7));
                *(uint4*)&dst[8 * c] = *(const uint4*)&smem[d * 128 + slot];
            }
        }
    } else {
        // ---- q/k region: RMSNorm over head dim + RoPE; q prescaled log2e/8 --
        const float* scv = (n0 < 1024) ? qs : ks;
        const float pre = (n0 < 1024) ? 0.18033688011112042f : 1.0f;
        float scl[4];
#pragma unroll
        for (int nt = 0; nt < 4; ++nt) scl[nt] = scv[16 * nt + mIdx];

#pragma unroll
        for (int mt = 0; mt < 4; ++mt) {
#pragma unroll
            for (int r = 0; r < 4; ++r) {
                float s = 0.f;
#pragma unroll
                for (int nt = 0; nt < 4; ++nt) {
                    float a = acc[mt][nt][r];
                    s += a * a;
                }
                s += __shfl_xor(s, 1);
                s += __shfl_xor(s, 2);
                s += __shfl_xor(s, 4);
                s += __shfl_xor(s, 8);
                float rn = rsqrtf(s * (1.f / 64.f) + 1e-6f);
                int R = m0 + 64 * wr + 16 * mt + quad * 4 + r;   // = b*L + l
                size_t peo = (size_t)R * 128;
#pragma unroll
                for (int nt = 0; nt < 4; ++nt) {
                    float v = acc[mt][nt][r] * rn * scl[nt];
                    float pp = __shfl_xor(v, 1);
                    float2 pw = *(const float2*)&pe[peo + 2 * (16 * nt + mIdx)];
                    float e  = (mIdx & 1) ? pp : v;
                    float od = (mIdx & 1) ? v : pp;
                    C[(size_t)R * N + n0 + 64 * wc + 16 * nt + mIdx] =
                        f2bf((pw.x * e + pw.y * od) * pre);
                }
            }
        }
    }
}

// ---------------- proj GEMM (global_load_lds staging, 64x128 tile) ------------
__global__ __launch_bounds__(256) void gemm_proj(
    const u16* __restrict__ A, const u16* __restrict__ Bt,
    const float* __restrict__ bias, float* __restrict__ C)
{
    __shared__ u16 sA[64 * 64];
    __shared__ u16 sB[128 * 64];

    const int tid = threadIdx.x;
    const int wave = tid >> 6, lane = tid & 63;
    const int mIdx = lane & 15, quad = lane >> 4;
    const int wr = wave >> 1, wc = wave & 1;   // 2x2 waves of 32x64
    const int m0 = blockIdx.y * 64, n0 = blockIdx.x * 128;
    const int N = DIMM, K = DIMM;
    const int lr = lane >> 3, lc = lane & 7;

    f32x4 acc[2][4];
#pragma unroll
    for (int a = 0; a < 2; ++a)
#pragma unroll
        for (int b = 0; b < 4; ++b) acc[a][b] = (f32x4){0.f, 0.f, 0.f, 0.f};

    for (int k0 = 0; k0 < K; k0 += 64) {
#pragma unroll
        for (int j = 0; j < 2; ++j) {       // A: 64 rows
            int r0 = 16 * wave + 8 * j + lr;
            int kc = 8 * (lc ^ (r0 & 7));
            gload16(&A[(size_t)(m0 + r0) * K + k0 + kc], &sA[(16 * wave + 8 * j) * 64]);
        }
#pragma unroll
        for (int j = 0; j < 4; ++j) {       // B: 128 rows
            int r0 = 32 * wave + 8 * j + lr;
            int kc = 8 * (lc ^ (r0 & 7));
            gload16(&Bt[(size_t)(n0 + r0) * K + k0 + kc], &sB[(32 * wave + 8 * j) * 64]);
        }
        __syncthreads();
#pragma unroll
        for (int ks2 = 0; ks2 < 2; ++ks2) {
            short8 af[2], bfr[4];
#pragma unroll
            for (int mt = 0; mt < 2; ++mt) {
                int Ra = 32 * wr + 16 * mt + mIdx;
                af[mt] = *(const short8*)&sA[Ra * 64 + 8 * ((ks2 * 4 + quad) ^ (Ra & 7))];
            }
#pragma unroll
            for (int nt = 0; nt < 4; ++nt) {
                int Rb = 64 * wc + 16 * nt + mIdx;
                bfr[nt] = *(const short8*)&sB[Rb * 64 + 8 * ((ks2 * 4 + quad) ^ (Rb & 7))];
            }
#pragma unroll
            for (int mt = 0; mt < 2; ++mt)
#pragma unroll
                for (int nt = 0; nt < 4; ++nt)
                    acc[mt][nt] = __builtin_amdgcn_mfma_f32_16x16x32_bf16(
                        af[mt], bfr[nt], acc[mt][nt], 0, 0, 0);
        }
        __syncthreads();
    }

#pragma unroll
    for (int mt = 0; mt < 2; ++mt)
#pragma unroll
        for (int r = 0; r < 4; ++r) {
            int row = m0 + 32 * wr + 16 * mt + quad * 4 + r;
#pragma unroll
            for (int nt = 0; nt < 4; ++nt) {
                int col = n0 + 64 * wc + 16 * nt + mIdx;
                C[(size_t)row * N + col] = acc[mt][nt][r] + bias[col];
            }
        }
}

// ---------------- flash attention, bf16 MFMA, S^T formulation (R5/R8 proven) --
// 512 threads = 8 waves; 128 q-rows/block; k-tiles of 64, double-buffered,
// 1 barrier/iter, prefetch = immediate global-load -> LDS-store (no cross-iter
// registers — R7 spill lesson; no single-buffer async — R10 latency lesson).
#define PR 72

__global__ __launch_bounds__(512, 4) void attn_mfma(
    const u16* __restrict__ qkv, const u16* __restrict__ vt, u16* __restrict__ o)
{
    __shared__ u16 sK[2][64 * PR];
    __shared__ u16 sVt[2][64 * PR];
    __shared__ u16 sP[128 * PR];

    const int tid = threadIdx.x;
    const int wave = tid >> 6;     // 0..7
    const int lane = tid & 63;
    const int mIdx = lane & 15;
    const int quad = lane >> 4;

    const int bh = blockIdx.x >> 4;   // 16 q-tiles of 128 rows per (b,h)
    const int qt = blockIdx.x & 15;
    const int b = bh >> 4, h = bh & 15;
    const int q0 = qt * 128;

    const u16* kbase = qkv + (size_t)b * LL * QKV_N + 1024 + h * 64;
    const u16* vbase = vt + (size_t)bh * 64 * LL;

    // Q fragment straight from global (wave-private rows); used as B-operand.
    const u16* qrow = qkv + (size_t)b * LL * QKV_N + h * 64
                      + (size_t)(q0 + 16 * wave + mIdx) * QKV_N;
    short8 aq0 = *(const short8*)&qrow[quad * 8];
    short8 aq1 = *(const short8*)&qrow[32 + quad * 8];

    // staging: 512 threads cover one 64x64 tile (1 uint4 each)
    const int sr = tid >> 3;        // row 0..63
    const int sc = (tid & 7) * 8;   // col chunk

    // preload tile 0
    {
        uint4 kv4 = *(const uint4*)&kbase[(size_t)sr * QKV_N + sc];
        uint4 vv4 = *(const uint4*)&vbase[(size_t)sr * LL + sc];
        *(uint4*)&sK[0][sr * PR + sc] = kv4;
        *(uint4*)&sVt[0][sr * PR + sc] = vv4;
    }

    float lsum = 0.f;
    f32x4 Oacc[4];
#pragma unroll
    for (int nb = 0; nb < 4; ++nb) Oacc[nb] = (f32x4){0.f, 0.f, 0.f, 0.f};

    u16* sProw = &sP[(16 * wave + mIdx) * PR];

    for (int kt = 0; kt < 32; ++kt) {
        const int p = kt & 1;
        __syncthreads();   // tile p staged; buffer p^1 free (read in iter kt-1)

        // prefetch tile kt+1 into buffer p^1 (overlaps compute below)
        if (kt + 1 < 32) {
            const int k0n = (kt + 1) * 64;
            uint4 kv4 = *(const uint4*)&kbase[(size_t)(k0n + sr) * QKV_N + sc];
            uint4 vv4 = *(const uint4*)&vbase[(size_t)sr * LL + k0n + sc];
            *(uint4*)&sK[p ^ 1][sr * PR + sc] = kv4;
            *(uint4*)&sVt[p ^ 1][sr * PR + sc] = vv4;
        }

        // ---- S^T strip: D[key][q] = mfma(A=K-frag, B=Q-frag) ----
#pragma unroll
        for (int nb = 0; nb < 4; ++nb) {
            short8 bk0 = *(const short8*)&sK[p][(16 * nb + mIdx) * PR + quad * 8];
            short8 bk1 = *(const short8*)&sK[p][(16 * nb + mIdx) * PR + 32 + quad * 8];
            f32x4 st = (f32x4){0.f, 0.f, 0.f, 0.f};
            st = __builtin_amdgcn_mfma_f32_16x16x32_bf16(bk0, aq0, st, 0, 0, 0);
            st = __builtin_amdgcn_mfma_f32_16x16x32_bf16(bk1, aq1, st, 0, 0, 0);

            float p0 = exp2f(st[0]), p1 = exp2f(st[1]);
            float p2 = exp2f(st[2]), p3 = exp2f(st[3]);
            lsum += (p0 + p1) + (p2 + p3);
            u32 w0 = pack_bf2(p0, p1);
            u32 w1 = pack_bf2(p2, p3);
            uint2 wpair; wpair.x = w0; wpair.y = w1;
            *(uint2*)&sProw[16 * nb + quad * 4] = wpair;
        }
        // sP rows are written and read by the same wave -> no barrier.

        // ---- O += P @ V ----
        short8 pa0 = *(const short8*)&sProw[quad * 8];
        short8 pa1 = *(const short8*)&sProw[32 + quad * 8];
#pragma unroll
        for (int nb = 0; nb < 4; ++nb) {
            short8 bv0 = *(const short8*)&sVt[p][(16 * nb + mIdx) * PR + quad * 8];
            short8 bv1 = *(const short8*)&sVt[p][(16 * nb + mIdx) * PR + 32 + quad * 8];
            Oacc[nb] = __builtin_amdgcn_mfma_f32_16x16x32_bf16(pa0, bv0, Oacc[nb], 0, 0, 0);
            Oacc[nb] = __builtin_amdgcn_mfma_f32_16x16x32_bf16(pa1, bv1, Oacc[nb], 0, 0, 0);
        }
    }

    // final l: reduce per-lane partial sums across the 4 quads (2 shuffles),
    // then each lane fetches l for its epilogue rows quad*4+r via shfl.
    lsum += __shfl_xor(lsum, 16);
    lsum += __shfl_xor(lsum, 32);

#pragma unroll
    for (int r = 0; r < 4; ++r) {
        float lr = __shfl(lsum, quad * 4 + r);   // lane (quad*4+r) has mIdx==quad*4+r
        float linv = 1.f / lr;
        int rowg = b * LL + q0 + 16 * wave + quad * 4 + r;
#pragma unroll
        for (int nb = 0; nb < 4; ++nb) {
            o[(size_t)rowg * DIMM + h * 64 + 16 * nb + mIdx] = f2bf(Oacc[nb][r] * linv);
        }
    }
}

extern "C" void kernel_launch(void* const* d_in, const int* in_sizes, int n_in,
                              void* d_out, int out_size, void* d_ws, size_t ws_size,
                              hipStream_t stream) {
    const float* x       = (const float*)d_in[0];
    const float* pe      = (const float*)d_in[1];
    const float* w_qkv   = (const float*)d_in[2];
    const float* q_scale = (const float*)d_in[3];
    const float* k_scale = (const float*)d_in[4];
    const float* w_proj  = (const float*)d_in[5];
    const float* b_proj  = (const float*)d_in[6];
    float* out = (float*)d_out;

    char* ws = (char*)d_ws;
    u16* qkv    = (u16*)ws;  ws += (size_t)4096 * 3072 * 2;
    u16* o      = (u16*)ws;  ws += (size_t)4096 * 1024 * 2;
    u16* xb     = (u16*)ws;  ws += (size_t)4096 * 1024 * 2;
    u16* wqkvt  = (u16*)ws;  ws += (size_t)3072 * 1024 * 2;
    u16* wprojt = (u16*)ws;  ws += (size_t)1024 * 1024 * 2;
    u16* vtbuf  = (u16*)ws;  ws += (size_t)BB * HH * DD * LL * 2;

    // 0. conversions
    convx<<<(4096 * 1024) / (256 * 8), 256, 0, stream>>>(x, xb);
    convt<<<dim3(1024 / 64, QKV_N / 64), 256, 0, stream>>>(w_qkv, wqkvt, DIMM, QKV_N);
    convt<<<dim3(1024 / 64, 1024 / 64), 256, 0, stream>>>(w_proj, wprojt, DIMM, DIMM);

    // 1. fused QKV projection + RMSNorm/RoPE (q,k) + V-transpose (v) epilogues
    gemm_qkv<<<dim3(QKV_N / 128, (BB * LL) / 128), 256, 0, stream>>>(
        xb, wqkvt, qkv, vtbuf, pe, q_scale, k_scale);

    // 2. attention (R5/R8-proven 16x16x32 MFMA, S^T formulation)
    attn_mfma<<<BB * HH * (LL / 128), 512, 0, stream>>>(qkv, vtbuf, o);

    // 3. output projection + bias (f32 out)
    gemm_proj<<<dim3(DIMM / 128, (BB * LL) / 64), 256, 0, stream>>>(
        o, wprojt, b_proj, out);
}